// Round 4
// baseline (4413.007 us; speedup 1.0000x reference)
//
#include <hip/hip_runtime.h>
#include <hip/hip_bf16.h>
#include <stdint.h>

#define B_ 64
#define S_ 512
#define I_ 256
#define H_ 512

typedef __attribute__((ext_vector_type(8))) short bf16x8;
typedef __attribute__((ext_vector_type(4))) float f32x4;

__device__ __forceinline__ ushort f2bf(float f) {
  union { float f; uint32_t u; } c; c.f = f;
  uint32_t u = c.u + 0x7FFFu + ((c.u >> 16) & 1u);
  return (ushort)(u >> 16);
}
__device__ __forceinline__ float bf2f(ushort s) {
  union { uint32_t u; float f; } c; c.u = ((uint32_t)s) << 16; return c.f;
}

// ---------------- weight convert (fp32 -> bf16), 3x 512x256 ----------------
// w_i{r,z,n} are (H,I) = 512x256 = 131,072 elements each.  (R3's fatal bug:
// used >>18 / 262,144 here -- that's the H x H recurrent size, not H x I.)
__global__ __launch_bounds__(256) void conv_w(const float* __restrict__ a,
                                              const float* __restrict__ b,
                                              const float* __restrict__ c,
                                              ushort* __restrict__ y) {
  int i = blockIdx.x * 256 + threadIdx.x;  // 98,304 groups of 4
  int e = i * 4;
  int g = e >> 17;           // 131,072 elems per matrix
  int rem = e & 131071;
  const float* src = (g == 0) ? a : (g == 1) ? b : c;
  float4 v = *(const float4*)(src + rem);
  ushort4 o;
  o.x = f2bf(v.x); o.y = f2bf(v.y); o.z = f2bf(v.z); o.w = f2bf(v.w);
  *(ushort4*)(y + e) = o;
}

// ---------------- input-projection GEMM (inline fp32->bf16 A conversion) ---
// C[m,n] = sum_k A[m,k]*Bw[n,k] + bias;  m = b*512+s (32768), n = g*512+h (1536), K=256
// output layout gi[s][g][b][h] (bf16) for streaming consumption by the scan.
__global__ __launch_bounds__(256) void gemm_gi(const float* __restrict__ A,
                                               const ushort* __restrict__ Bw,
                                               const float* __restrict__ b_ir,
                                               const float* __restrict__ b_iz,
                                               const float* __restrict__ b_in,
                                               ushort* __restrict__ gi) {
  __shared__ ushort As[128][40];  // +8 pad
  __shared__ ushort Bs[128][40];
  const int m0 = blockIdx.x * 128;
  const int n0 = blockIdx.y * 128;
  const int tid = threadIdx.x;
  const int lane = tid & 63, wid = tid >> 6;
  const int wm = wid & 1, wn = wid >> 1;
  f32x4 acc[4][4];
  const f32x4 zz = {0.f, 0.f, 0.f, 0.f};
#pragma unroll
  for (int mi = 0; mi < 4; mi++)
#pragma unroll
    for (int ni = 0; ni < 4; ni++) acc[mi][ni] = zz;

  const int r = tid >> 2;
  const int ccol = (tid & 3) * 8;
  for (int kk = 0; kk < 256; kk += 32) {
    __syncthreads();
#pragma unroll
    for (int half = 0; half < 2; half++) {
      const float* ap = &A[(size_t)(m0 + r + half * 64) * 256 + kk + ccol];
      float4 x0 = *(const float4*)ap;
      float4 x1 = *(const float4*)(ap + 4);
      union { ushort u[8]; uint4 v; } pk;
      pk.u[0] = f2bf(x0.x); pk.u[1] = f2bf(x0.y); pk.u[2] = f2bf(x0.z); pk.u[3] = f2bf(x0.w);
      pk.u[4] = f2bf(x1.x); pk.u[5] = f2bf(x1.y); pk.u[6] = f2bf(x1.z); pk.u[7] = f2bf(x1.w);
      *(uint4*)&As[r + half * 64][ccol] = pk.v;
    }
    *(uint4*)&Bs[r][ccol]      = *(const uint4*)&Bw[(size_t)(n0 + r) * 256 + kk + ccol];
    *(uint4*)&Bs[r + 64][ccol] = *(const uint4*)&Bw[(size_t)(n0 + r + 64) * 256 + kk + ccol];
    __syncthreads();
    const int q8 = (lane >> 4) * 8;
    bf16x8 af[4], bf[4];
#pragma unroll
    for (int mi = 0; mi < 4; mi++)
      af[mi] = *(const bf16x8*)&As[wm * 64 + mi * 16 + (lane & 15)][q8];
#pragma unroll
    for (int ni = 0; ni < 4; ni++)
      bf[ni] = *(const bf16x8*)&Bs[wn * 64 + ni * 16 + (lane & 15)][q8];
#pragma unroll
    for (int mi = 0; mi < 4; mi++)
#pragma unroll
      for (int ni = 0; ni < 4; ni++)
        acc[mi][ni] = __builtin_amdgcn_mfma_f32_16x16x32_bf16(af[mi], bf[ni], acc[mi][ni], 0, 0, 0);
  }
#pragma unroll
  for (int ni = 0; ni < 4; ni++) {
    int n = n0 + wn * 64 + ni * 16 + (lane & 15);
    int g = n >> 9, hh = n & 511;
    const float* bp = (g == 0) ? b_ir : (g == 1) ? b_iz : b_in;
    float bias = bp[hh];
#pragma unroll
    for (int mi = 0; mi < 4; mi++) {
      int mb = m0 + wm * 64 + mi * 16 + ((lane >> 4) << 2);
#pragma unroll
      for (int v = 0; v < 4; v++) {
        int m = mb + v;
        int s = m & 511, b = m >> 9;
        size_t idx = (((size_t)s * 3 + g) * 64 + b) * 512 + hh;
        gi[idx] = f2bf(acc[mi][ni][v] + bias);
      }
    }
  }
}

// ---------------- flag init via sc1 stores (no dirty-L2 lines) -------------
__global__ __launch_bounds__(256) void init_flags(uint32_t* __restrict__ p) {
  int i = blockIdx.x * 256 + threadIdx.x;  // 513*64*4 = 131,328 exactly
  __hip_atomic_store(p + i, 0u, __ATOMIC_RELAXED, __HIP_MEMORY_SCOPE_AGENT);
}

// ---------------- persistent scan: batched flag protocol -------------------
// 4 batch-groups x 16 WGs; WG (g,cc) owns rows [16g,16g+16) x cols [32cc,32cc+32).
// h ping-pong: 2 slots of 64x512 bf16 (h(t) lives in slot t&1).
// Signaling: flags[t][group][cc*4+wave].  Writer wave: sc1 data stores ->
// per-wave s_waitcnt vmcnt(0) -> lane0 sc1 flag store.  Reader: each lane
// polls one of the 64 flags (ONE round-trip per retry), then ONE batched
// 64-dword sc1 read of h (guaranteed present: flag implies drained to L3).
// Slot reuse safe (R2-proven): writer finishing step t consumed flags(t) =>
// all WGs published h(t) => all done reading h(t-1) => slot (t+1)&1 is dead.
#define SLOT_DW (B_ * H_ / 2)  // 16384 dwords per slot

__global__ __launch_bounds__(256, 1) void gru_scan(
    const float* __restrict__ h0p, const float* __restrict__ w_hr,
    const float* __restrict__ w_hz, const float* __restrict__ w_hn,
    const float* __restrict__ b_hr, const float* __restrict__ b_hz,
    const float* __restrict__ b_hn, const ushort* __restrict__ gi,
    uint32_t* __restrict__ hstream, uint32_t* __restrict__ flags,
    float* __restrict__ out) {
  const int bid = blockIdx.x;
  const int group = bid >> 4, cc = bid & 15;
  const int b0 = group * 16;
  const int hc0 = cc * 32;
  const int tid = threadIdx.x, lane = tid & 63, wid = tid >> 6;

  __shared__ float atile[2][3][16][33];

  // elementwise ownership: row gm (0..15), cols gn0, gn0+1
  const int gm = tid >> 4, gn0 = (tid & 15) * 2;

  const float bhr0 = b_hr[hc0 + gn0], bhr1 = b_hr[hc0 + gn0 + 1];
  const float bhz0 = b_hz[hc0 + gn0], bhz1 = b_hz[hc0 + gn0 + 1];
  const float bhn0 = b_hn[hc0 + gn0], bhn1 = b_hn[hc0 + gn0 + 1];
  float2 h01 = *(const float2*)&h0p[(size_t)(b0 + gm) * H_ + hc0 + gn0];
  float hprev0 = h01.x, hprev1 = h01.y;

  // Recurrent-weight B-fragments, resident in VGPRs for the whole kernel.
  // Wave w<3 = gate w, col-tiles j=0,1 at hc0 + j*16 + (lane&15); k = ks*32 + (lane>>4)*8 + [0..7]
  bf16x8 bfrag[2][16];
  if (wid < 3) {
    const float* W = (wid == 0) ? w_hr : (wid == 1) ? w_hz : w_hn;
#pragma unroll
    for (int j = 0; j < 2; j++) {
      int row = hc0 + j * 16 + (lane & 15);
      const float* Wr = W + (size_t)row * H_ + ((lane >> 4) << 3);
#pragma unroll
      for (int ks = 0; ks < 16; ks++) {
        const float4 x = *(const float4*)(Wr + ks * 32);
        const float4 y = *(const float4*)(Wr + ks * 32 + 4);
        bf16x8 f;
        f[0] = (short)f2bf(x.x); f[1] = (short)f2bf(x.y);
        f[2] = (short)f2bf(x.z); f[3] = (short)f2bf(x.w);
        f[4] = (short)f2bf(y.x); f[5] = (short)f2bf(y.y);
        f[6] = (short)f2bf(y.z); f[7] = (short)f2bf(y.w);
        bfrag[j][ks] = f;
      }
    }
  }

  // publish h0 into slot 0: sc1 stores -> per-wave drain -> per-wave flag
  {
    uint32_t packed = (uint32_t)f2bf(hprev0) | ((uint32_t)f2bf(hprev1) << 16);
    uint32_t* dst = hstream + (((size_t)(b0 + gm) * H_ + hc0 + gn0) >> 1);
    __hip_atomic_store(dst, packed, __ATOMIC_RELAXED, __HIP_MEMORY_SCOPE_AGENT);
  }
  asm volatile("s_waitcnt vmcnt(0)" ::: "memory");
  if (lane == 0)
    __hip_atomic_store(&flags[(size_t)(0 * 4 + group) * 64 + cc * 4 + wid], 1u,
                       __ATOMIC_RELAXED, __HIP_MEMORY_SCOPE_AGENT);

  const uint32_t* gp = (const uint32_t*)gi;

  for (int t = 0; t < S_; t++) {
    // gi prefetch for this step (independent of h; overlaps the poll below)
    size_t gdw = ((((size_t)t * 3) * B_ + (b0 + gm)) * H_ + hc0 + gn0) >> 1;
    uint32_t gr = gp[gdw];
    uint32_t gz = gp[gdw + (B_ * H_ / 2)];
    uint32_t gn_ = gp[gdw + (B_ * H_)];

    if (wid < 3) {
      // poll the 64 per-wave flags for (t, group): one RT per retry
      uint32_t* fl = flags + ((size_t)t * 4 + group) * 64;
      while (true) {
        uint32_t f = __hip_atomic_load(fl + lane, __ATOMIC_RELAXED,
                                       __HIP_MEMORY_SCOPE_AGENT);
        if (__all(f != 0)) break;
      }
      // one batched read of this wave's 64 h-dwords (flag => data at L3)
      uint32_t* hb = hstream + (size_t)(t & 1) * SLOT_DW + b0 * (H_ / 2) +
                     (lane & 15) * (H_ / 2) + ((lane >> 4) << 2);
      uint32_t d[16][4];
#pragma unroll
      for (int ks = 0; ks < 16; ks++)
#pragma unroll
        for (int i = 0; i < 4; i++)
          d[ks][i] = __hip_atomic_load(hb + ks * 16 + i, __ATOMIC_RELAXED,
                                       __HIP_MEMORY_SCOPE_AGENT);
      f32x4 acc0 = {0.f, 0.f, 0.f, 0.f}, acc1 = {0.f, 0.f, 0.f, 0.f};
#pragma unroll
      for (int ks = 0; ks < 16; ks++) {
        union { uint32_t u[4]; bf16x8 v; } a;
        a.u[0] = d[ks][0]; a.u[1] = d[ks][1]; a.u[2] = d[ks][2]; a.u[3] = d[ks][3];
        acc0 = __builtin_amdgcn_mfma_f32_16x16x32_bf16(a.v, bfrag[0][ks], acc0, 0, 0, 0);
        acc1 = __builtin_amdgcn_mfma_f32_16x16x32_bf16(a.v, bfrag[1][ks], acc1, 0, 0, 0);
      }
      const int rr = (lane >> 4) << 2, nn0 = lane & 15;
#pragma unroll
      for (int v = 0; v < 4; v++) {
        atile[t & 1][wid][rr + v][nn0] = acc0[v];
        atile[t & 1][wid][rr + v][16 + nn0] = acc1[v];
      }
    }
    __syncthreads();  // atile handoff (double-buffered -> one barrier/step)

    float ar0 = atile[t & 1][0][gm][gn0], ar1 = atile[t & 1][0][gm][gn0 + 1];
    float az0 = atile[t & 1][1][gm][gn0], az1 = atile[t & 1][1][gm][gn0 + 1];
    float an0 = atile[t & 1][2][gm][gn0], an1 = atile[t & 1][2][gm][gn0 + 1];

    float r0 = 1.f / (1.f + __expf(-(bf2f((ushort)(gr & 0xFFFF)) + ar0 + bhr0)));
    float r1 = 1.f / (1.f + __expf(-(bf2f((ushort)(gr >> 16)) + ar1 + bhr1)));
    float z0 = 1.f / (1.f + __expf(-(bf2f((ushort)(gz & 0xFFFF)) + az0 + bhz0)));
    float z1 = 1.f / (1.f + __expf(-(bf2f((ushort)(gz >> 16)) + az1 + bhz1)));
    float na0 = bf2f((ushort)(gn_ & 0xFFFF)) + r0 * (an0 + bhn0);
    float na1 = bf2f((ushort)(gn_ >> 16)) + r1 * (an1 + bhn1);
    float n0 = 2.f / (1.f + __expf(-2.f * na0)) - 1.f;
    float n1 = 2.f / (1.f + __expf(-2.f * na1)) - 1.f;
    float hnew0 = (1.f - z0) * n0 + z0 * hprev0;
    float hnew1 = (1.f - z1) * n1 + z1 * hprev1;
    hprev0 = hnew0; hprev1 = hnew1;

    // publish h(t+1): sc1 data stores -> per-wave drain -> per-wave flag
    {
      uint32_t packed = (uint32_t)f2bf(hnew0) | ((uint32_t)f2bf(hnew1) << 16);
      uint32_t* dst = hstream + (size_t)((t + 1) & 1) * SLOT_DW +
                      (((size_t)(b0 + gm) * H_ + hc0 + gn0) >> 1);
      __hip_atomic_store(dst, packed, __ATOMIC_RELAXED, __HIP_MEMORY_SCOPE_AGENT);
    }
    asm volatile("s_waitcnt vmcnt(0)" ::: "memory");
    if (lane == 0)
      __hip_atomic_store(&flags[(size_t)(t + 1) * 4 * 64 + group * 64 + cc * 4 + wid],
                         1u, __ATOMIC_RELAXED, __HIP_MEMORY_SCOPE_AGENT);

    // out stores (never read back; cached, off the sync critical path)
    *(float2*)&out[((size_t)(b0 + gm) * S_ + t) * H_ + hc0 + gn0] =
        make_float2(hnew0, hnew1);
    if (t == S_ - 1)
      *(float2*)&out[(size_t)B_ * S_ * H_ + (size_t)(b0 + gm) * H_ + hc0 + gn0] =
          make_float2(hnew0, hnew1);
  }
}

// ---------------- launcher ----------------
extern "C" void kernel_launch(void* const* d_in, const int* in_sizes, int n_in,
                              void* d_out, int out_size, void* d_ws, size_t ws_size,
                              hipStream_t stream) {
  const float* inputs = (const float*)d_in[0];
  const float* hid    = (const float*)d_in[1];
  const float* w_ir   = (const float*)d_in[2];
  const float* w_iz   = (const float*)d_in[3];
  const float* w_in   = (const float*)d_in[4];
  const float* b_ir   = (const float*)d_in[5];
  const float* b_iz   = (const float*)d_in[6];
  const float* b_in   = (const float*)d_in[7];
  const float* w_hr   = (const float*)d_in[8];
  const float* w_hz   = (const float*)d_in[9];
  const float* w_hn   = (const float*)d_in[10];
  const float* b_hr   = (const float*)d_in[11];
  const float* b_hz   = (const float*)d_in[12];
  const float* b_hn   = (const float*)d_in[13];
  float* out = (float*)d_out;

  char* ws = (char*)d_ws;
  ushort*   wsW  = (ushort*)(ws);                 // W_i bf16:      786,432 B
  ushort*   wsGi = (ushort*)(ws + 786432);        // gi bf16:   100,663,296 B
  uint32_t* wsH  = (uint32_t*)(ws + 101449728);   // h ping-pong:   131,072 B
  uint32_t* wsF  = (uint32_t*)(ws + 101580800);   // flags 513*4*64: 525,312 B
                                                  // total:     102,106,112 B

  init_flags<<<513, 256, 0, stream>>>(wsF);
  conv_w<<<384, 256, 0, stream>>>(w_ir, w_iz, w_in, wsW);
  gemm_gi<<<dim3(256, 12), 256, 0, stream>>>(inputs, wsW, b_ir, b_iz, b_in, wsGi);
  gru_scan<<<64, 256, 0, stream>>>(hid, w_hr, w_hz, w_hn, b_hr, b_hz, b_hn,
                                   wsGi, wsH, wsF, out);
}